// Round 1
// baseline (2942.374 us; speedup 1.0000x reference)
//
#include <hip/hip_runtime.h>
#include <cstddef>

// ---------------------------------------------------------------------------
// VGG-ish forward, fp32 baseline. B=64 fixed.
// Layout NCHW throughout, matching the reference.
// ---------------------------------------------------------------------------

constexpr int BATCH = 64;

// Generic 3x3 SAME conv, stride 1.
// Block = 256 threads = 4 waves. Each wave handles OCW output channels
// (wave-uniform -> weights via scalar loads). Lane owns either a 2x2 quad
// (POOL: fused relu+maxpool2) or a 1x4 strip (float4 stores, relu fused).
// KS>1: K-split over CIN; writes raw partials (no bias/relu) to
// out[ks][B][COUT][HW*HW]; a combine kernel finishes.
template<int CIN, int COUT, int HW, int TILE, int IPB, int OCW, bool POOL, int KS, int CIC>
__global__ __launch_bounds__(256)
void conv3x3(const float* __restrict__ in, const float* __restrict__ wg,
             const float* __restrict__ bias, float* __restrict__ out)
{
    constexpr int NT   = HW / TILE;     // tiles per spatial dim
    constexpr int T2   = TILE + 2;      // padded tile (halo)
    constexpr int LDW  = T2 + 1;        // LDS row pitch (+1 bank stagger)
    constexpr int CIPS = CIN / KS;      // input channels per K-slice
    static_assert(CIPS % CIC == 0, "chunking");
    static_assert((POOL ? (TILE/2)*(TILE/2) : TILE*(TILE/4)) * IPB == 64, "lane map");
    static_assert(COUT % (4*OCW) == 0, "co blocking");

    __shared__ float ins[IPB][CIC][T2][LDW];

    const int tid  = threadIdx.x;
    const int lane = tid & 63;
    const int wv   = __builtin_amdgcn_readfirstlane(tid >> 6);  // force SGPR

    const int tile = blockIdx.x % (NT*NT);
    const int ig   = blockIdx.x / (NT*NT);
    const int ty0  = (tile / NT) * TILE;
    const int tx0  = (tile % NT) * TILE;
    const int b0   = ig * IPB;
    const int co0  = (blockIdx.y * 4 + wv) * OCW;               // scalar
    const int ks   = (KS > 1) ? (int)blockIdx.z : 0;

    int il, py0, px0;
    if (POOL) {
        constexpr int QW  = TILE/2;
        constexpr int QPI = QW*QW;
        il = lane / QPI;
        int q = lane % QPI;
        py0 = (q / QW) * 2;
        px0 = (q % QW) * 2;
    } else {
        constexpr int SPR = TILE/4;
        constexpr int SPI = TILE*SPR;
        il = lane / SPI;
        int s = lane % SPI;
        py0 = s / SPR;
        px0 = (s % SPR) * 4;
    }

    float acc[4][OCW];
    #pragma unroll
    for (int i = 0; i < 4; i++)
        #pragma unroll
        for (int j = 0; j < OCW; j++) acc[i][j] = 0.f;

    const int ci_begin = ks * CIPS;
    for (int ci0 = ci_begin; ci0 < ci_begin + CIPS; ci0 += CIC) {
        __syncthreads();
        constexpr int E = IPB*CIC*T2*T2;
        for (int l = tid; l < E; l += 256) {
            int xx = l % T2;
            int r1 = l / T2;
            int yy = r1 % T2;
            int r2 = r1 / T2;
            int ci = r2 % CIC;
            int im = r2 / CIC;
            int gy = ty0 + yy - 1;
            int gx = tx0 + xx - 1;
            float v = 0.f;
            if (gy >= 0 && gy < HW && gx >= 0 && gx < HW)
                v = in[(((size_t)(b0+im)*CIN + (ci0+ci))*HW + gy)*HW + gx];
            ins[im][ci][yy][xx] = v;
        }
        __syncthreads();

        #pragma unroll 1   // keep body I$-resident
        for (int ci = 0; ci < CIC; ci++) {
            if constexpr (POOL) {
                float p[4][4];
                #pragma unroll
                for (int dy = 0; dy < 4; dy++)
                    #pragma unroll
                    for (int dx = 0; dx < 4; dx++)
                        p[dy][dx] = ins[il][ci][py0+dy][px0+dx];
                #pragma unroll
                for (int j = 0; j < OCW; j++) {
                    const float* wp = wg + ((size_t)(co0+j)*CIN + (ci0+ci))*9;
                    float w0=wp[0],w1=wp[1],w2=wp[2],w3=wp[3],w4=wp[4],
                          w5=wp[5],w6=wp[6],w7=wp[7],w8=wp[8];
                    #pragma unroll
                    for (int oy = 0; oy < 2; oy++)
                        #pragma unroll
                        for (int ox = 0; ox < 2; ox++)
                            acc[oy*2+ox][j] +=
                                p[oy+0][ox+0]*w0 + p[oy+0][ox+1]*w1 + p[oy+0][ox+2]*w2 +
                                p[oy+1][ox+0]*w3 + p[oy+1][ox+1]*w4 + p[oy+1][ox+2]*w5 +
                                p[oy+2][ox+0]*w6 + p[oy+2][ox+1]*w7 + p[oy+2][ox+2]*w8;
                }
            } else {
                float p[3][6];
                #pragma unroll
                for (int dy = 0; dy < 3; dy++)
                    #pragma unroll
                    for (int dx = 0; dx < 6; dx++)
                        p[dy][dx] = ins[il][ci][py0+dy][px0+dx];
                #pragma unroll
                for (int j = 0; j < OCW; j++) {
                    const float* wp = wg + ((size_t)(co0+j)*CIN + (ci0+ci))*9;
                    float w0=wp[0],w1=wp[1],w2=wp[2],w3=wp[3],w4=wp[4],
                          w5=wp[5],w6=wp[6],w7=wp[7],w8=wp[8];
                    #pragma unroll
                    for (int ox = 0; ox < 4; ox++)
                        acc[ox][j] +=
                            p[0][ox+0]*w0 + p[0][ox+1]*w1 + p[0][ox+2]*w2 +
                            p[1][ox+0]*w3 + p[1][ox+1]*w4 + p[1][ox+2]*w5 +
                            p[2][ox+0]*w6 + p[2][ox+1]*w7 + p[2][ox+2]*w8;
                }
            }
        }
    }

    if constexpr (KS > 1) {
        // raw partials, strip layout, no bias/relu
        #pragma unroll
        for (int j = 0; j < OCW; j++) {
            size_t idx = ((((size_t)ks*BATCH + (b0+il))*COUT + (co0+j))*HW + (ty0+py0))*HW + (tx0+px0);
            float4 v = make_float4(acc[0][j], acc[1][j], acc[2][j], acc[3][j]);
            *reinterpret_cast<float4*>(&out[idx]) = v;
        }
    } else if constexpr (POOL) {
        constexpr int HWO = HW/2;
        #pragma unroll
        for (int j = 0; j < OCW; j++) {
            float bb = bias[co0+j];
            float m = fmaxf(fmaxf(acc[0][j], acc[1][j]), fmaxf(acc[2][j], acc[3][j])) + bb;
            m = fmaxf(m, 0.f);  // relu(max+b) == max(relu(+b)), relu monotone
            size_t idx = (((size_t)(b0+il)*COUT + (co0+j))*HWO + (ty0+py0)/2)*HWO + (tx0+px0)/2;
            out[idx] = m;
        }
    } else {
        #pragma unroll
        for (int j = 0; j < OCW; j++) {
            float bb = bias[co0+j];
            float4 v = make_float4(fmaxf(acc[0][j]+bb, 0.f), fmaxf(acc[1][j]+bb, 0.f),
                                   fmaxf(acc[2][j]+bb, 0.f), fmaxf(acc[3][j]+bb, 0.f));
            size_t idx = (((size_t)(b0+il)*COUT + (co0+j))*HW + (ty0+py0))*HW + (tx0+px0);
            *reinterpret_cast<float4*>(&out[idx]) = v;
        }
    }
}

// Sum KS partials + bias + relu.  Layout [KS][B][512][16] -> [B][512][4][4]
template<int KS>
__global__ __launch_bounds__(256)
void combine_relu(const float* __restrict__ part, const float* __restrict__ bias,
                  float* __restrict__ out)
{
    constexpr int TOTAL = BATCH*512*16;
    int i = blockIdx.x*256 + threadIdx.x;
    if (i >= TOTAL) return;
    int co = (i >> 4) & 511;
    float s = bias[co];
    #pragma unroll
    for (int k = 0; k < KS; k++) s += part[(size_t)k*TOTAL + i];
    out[i] = fmaxf(s, 0.f);
}

// mask[b][c] = 1 if c in b_table[y[b]] else 0.  (sort in ref is a no-op for the mask)
__global__ void build_mask(const int* __restrict__ y, const int* __restrict__ btab,
                           float* __restrict__ mask)
{
    __shared__ float m[512];
    int b = blockIdx.x;
    int t = threadIdx.x;               // 128 threads
    for (int i = t; i < 512; i += 128) m[i] = 0.f;
    __syncthreads();
    int cls = y[b];
    int idx = btab[cls*128 + t];
    m[idx] = 1.0f;                     // benign same-value races
    __syncthreads();
    for (int i = t; i < 512; i += 128) mask[b*512 + i] = m[i];
}

// pool2(h4b)*mask, flattened [B,2048] but written TRANSPOSED: xt[k][b]
__global__ __launch_bounds__(256)
void poolmask_xt(const float* __restrict__ h, const float* __restrict__ mask,
                 float* __restrict__ xt)
{
    int i = blockIdx.x*256 + threadIdx.x;   // over 64*2048
    if (i >= BATCH*2048) return;
    int b = i / 2048;
    int k = i % 2048;                       // c*4 + py*2 + px
    int c  = k >> 2;
    int py = (k >> 1) & 1, px = k & 1;
    const float* hp = h + (((size_t)b*512 + c)*4 + 2*py)*4 + 2*px;
    float mx = fmaxf(fmaxf(hp[0], hp[1]), fmaxf(hp[4], hp[5]));
    xt[(size_t)k*64 + b] = mask[b*512 + c] * mx;
}

// FC: out[r][c] = sum_k xt[k][r] * w[c][k] + bias[c].
// Block = 4 waves: wave = (col-group of 8) x (K-half). lane = batch row.
// x loads coalesced (lane-contiguous), w loads wave-uniform -> scalar.
template<int K, int N, bool RELU, bool TROUT>
__global__ __launch_bounds__(256)
void fc_kernel(const float* __restrict__ xt, const float* __restrict__ w,
               const float* __restrict__ bias, float* __restrict__ out)
{
    __shared__ float red[4][8][64];
    const int tid  = threadIdx.x;
    const int lane = tid & 63;
    const int wv   = __builtin_amdgcn_readfirstlane(tid >> 6);
    const int cg   = wv >> 1;
    const int kh   = wv & 1;
    const int c0   = blockIdx.x*16 + cg*8;

    const float* wrow[8];
    #pragma unroll
    for (int i = 0; i < 8; i++) {
        int c = c0 + i; if (c > N-1) c = N-1;   // clamp (fc3 tail), avoids OOB
        wrow[i] = w + (size_t)c*K;
    }

    float acc[8];
    #pragma unroll
    for (int i = 0; i < 8; i++) acc[i] = 0.f;

    const int k0 = kh*(K/2);
    for (int k = k0; k < k0 + K/2; k += 4) {
        float x0 = xt[(size_t)(k+0)*64 + lane];
        float x1 = xt[(size_t)(k+1)*64 + lane];
        float x2 = xt[(size_t)(k+2)*64 + lane];
        float x3 = xt[(size_t)(k+3)*64 + lane];
        #pragma unroll
        for (int i = 0; i < 8; i++)
            acc[i] += x0*wrow[i][k+0] + x1*wrow[i][k+1] + x2*wrow[i][k+2] + x3*wrow[i][k+3];
    }
    #pragma unroll
    for (int i = 0; i < 8; i++) red[wv][i][lane] = acc[i];
    __syncthreads();
    if (kh == 0) {
        #pragma unroll
        for (int i = 0; i < 8; i++) {
            int c = c0 + i;
            if (c < N) {
                float v = red[wv][i][lane] + red[wv+1][i][lane] + bias[c];
                if (RELU) v = fmaxf(v, 0.f);
                if (TROUT) out[(size_t)c*64 + lane] = v;
                else       out[(size_t)lane*N + c] = v;
            }
        }
    }
}

extern "C" void kernel_launch(void* const* d_in, const int* in_sizes, int n_in,
                              void* d_out, int out_size, void* d_ws, size_t ws_size,
                              hipStream_t stream)
{
    const float* x    = (const float*)d_in[0];
    const int*   y    = (const int*)  d_in[1];
    const int*   btab = (const int*)  d_in[2];
    const float* cw0  = (const float*)d_in[3];  const float* cb0  = (const float*)d_in[4];
    const float* cw1  = (const float*)d_in[5];  const float* cb1  = (const float*)d_in[6];
    const float* cw2a = (const float*)d_in[7];  const float* cb2a = (const float*)d_in[8];
    const float* cw2b = (const float*)d_in[9];  const float* cb2b = (const float*)d_in[10];
    const float* cw3a = (const float*)d_in[11]; const float* cb3a = (const float*)d_in[12];
    const float* cw3b = (const float*)d_in[13]; const float* cb3b = (const float*)d_in[14];
    const float* cw4a = (const float*)d_in[15]; const float* cb4a = (const float*)d_in[16];
    const float* cw4b = (const float*)d_in[17]; const float* cb4b = (const float*)d_in[18];
    const float* fw1  = (const float*)d_in[19]; const float* fb1  = (const float*)d_in[20];
    const float* fw2  = (const float*)d_in[21]; const float* fb2  = (const float*)d_in[22];
    const float* fw3  = (const float*)d_in[23]; const float* fb3  = (const float*)d_in[24];

    float* ws = (float*)d_ws;
    float* A  = ws;                   // 4,194,304 f  (max: [64,256,16,16] / [64,64,32,32])
    float* Bb = A  + 4194304;         // 2,097,152 f  (max: [64,128,16,16])
    float* P  = Bb + 2097152;         // 4,194,304 f  (conv4 partials, KS=8)
    float* M  = P  + 4194304;         // 32,768 f     (mask [64,512])
    float* X0 = M  + 32768;           // 131,072 f    (fc1 in, [2048][64])
    float* X1 = X0 + 131072;          // 262,144 f    (fc2 in, [4096][64])
    float* X2 = X1 + 262144;          // 262,144 f    (fc3 in, [4096][64])
    (void)ws_size; (void)in_sizes; (void)n_in; (void)out_size;

    // conv0 + relu + pool : x[64,3,64,64] -> A[64,64,32,32]
    conv3x3<3,64,64,16,1,16,true,1,3><<<dim3(16*64,1,1),256,0,stream>>>(x, cw0, cb0, A);
    // conv1 + relu + pool : A -> Bb[64,128,16,16]
    conv3x3<64,128,32,16,1,8,true,1,8><<<dim3(4*64,4,1),256,0,stream>>>(A, cw1, cb1, Bb);
    // conv2a + relu : Bb -> A[64,256,16,16]
    conv3x3<128,256,16,16,1,8,false,1,8><<<dim3(64,8,1),256,0,stream>>>(Bb, cw2a, cb2a, A);
    // conv2b + relu + pool : A -> Bb[64,256,8,8]
    conv3x3<256,256,16,16,1,8,true,1,8><<<dim3(64,8,1),256,0,stream>>>(A, cw2b, cb2b, Bb);
    // conv3a + relu : Bb -> A[64,512,8,8]
    conv3x3<256,512,8,8,4,4,false,1,8><<<dim3(16,32,1),256,0,stream>>>(Bb, cw3a, cb3a, A);
    // conv3b + relu + pool : A -> Bb[64,512,4,4]
    conv3x3<512,512,8,8,4,4,true,1,8><<<dim3(16,32,1),256,0,stream>>>(A, cw3b, cb3b, Bb);
    // conv4a (K-split 8) : Bb -> P ; combine -> A[64,512,4,4] (relu)
    conv3x3<512,512,4,4,16,8,false,8,8><<<dim3(4,16,8),256,0,stream>>>(Bb, cw4a, cb4a, P);
    combine_relu<8><<<2048,256,0,stream>>>(P, cb4a, A);
    // conv4b (K-split 8) : A -> P ; combine -> Bb[64,512,4,4] (relu)
    conv3x3<512,512,4,4,16,8,false,8,8><<<dim3(4,16,8),256,0,stream>>>(A, cw4b, cb4b, P);
    combine_relu<8><<<2048,256,0,stream>>>(P, cb4b, Bb);
    // engram mask
    build_mask<<<64,128,0,stream>>>(y, btab, M);
    // pool + mask + flatten (transposed for FC)
    poolmask_xt<<<512,256,0,stream>>>(Bb, M, X0);
    // classifier
    fc_kernel<2048,4096,true, true ><<<256,256,0,stream>>>(X0, fw1, fb1, X1);
    fc_kernel<4096,4096,true, true ><<<256,256,0,stream>>>(X1, fw2, fb2, X2);
    fc_kernel<4096,1000,false,false><<<63, 256,0,stream>>>(X2, fw3, fb3, (float*)d_out);
}

// Round 2
// 1166.309 us; speedup vs baseline: 2.5228x; 2.5228x over previous
//
#include <hip/hip_runtime.h>
#include <hip/hip_bf16.h>
#include <cstddef>

typedef __attribute__((ext_vector_type(8))) short short8;
typedef __attribute__((ext_vector_type(4))) float fx4;
typedef __attribute__((ext_vector_type(4))) unsigned short us4;
typedef __attribute__((ext_vector_type(8))) unsigned short us8;

constexpr int BATCH = 64;

static __device__ __forceinline__ unsigned short f2bf(float x) {
    __hip_bfloat16 h = __float2bfloat16(x);
    return *reinterpret_cast<unsigned short*>(&h);
}

// ---------------------------------------------------------------------------
// conv0: CIN=3 fp32 VALU conv + relu + pool, emits NHWC bf16 [64][32][32][64]
// ---------------------------------------------------------------------------
__global__ __launch_bounds__(256)
void conv0_kernel(const float* __restrict__ x, const float* __restrict__ w,
                  const float* __restrict__ bias, unsigned short* __restrict__ out)
{
    __shared__ float ins[3][18][19];
    const int tid  = threadIdx.x;
    const int lane = tid & 63;
    const int wv   = __builtin_amdgcn_readfirstlane(tid >> 6);
    const int img  = blockIdx.x >> 4;
    const int tile = blockIdx.x & 15;
    const int ty0  = (tile >> 2) * 16, tx0 = (tile & 3) * 16;
    const int py0  = (lane >> 3) * 2,  px0 = (lane & 7) * 2;
    const int co0  = wv * 16;

    for (int t = tid; t < 3*18*18; t += 256) {
        int xx = t % 18, yy = (t/18) % 18, ci = t/(18*18);
        int gy = ty0 + yy - 1, gx = tx0 + xx - 1;
        float v = 0.f;
        if (gy >= 0 && gy < 64 && gx >= 0 && gx < 64)
            v = x[((img*3 + ci)*64 + gy)*64 + gx];
        ins[ci][yy][xx] = v;
    }
    __syncthreads();

    float acc[16][4];
    #pragma unroll
    for (int j = 0; j < 16; j++)
        #pragma unroll
        for (int r = 0; r < 4; r++) acc[j][r] = 0.f;

    #pragma unroll
    for (int ci = 0; ci < 3; ci++) {
        float p[4][4];
        #pragma unroll
        for (int dy = 0; dy < 4; dy++)
            #pragma unroll
            for (int dx = 0; dx < 4; dx++)
                p[dy][dx] = ins[ci][py0+dy][px0+dx];
        #pragma unroll
        for (int j = 0; j < 16; j++) {
            const float* wp = w + ((co0+j)*3 + ci)*9;
            float w0=wp[0],w1=wp[1],w2=wp[2],w3=wp[3],w4=wp[4],
                  w5=wp[5],w6=wp[6],w7=wp[7],w8=wp[8];
            #pragma unroll
            for (int oy = 0; oy < 2; oy++)
                #pragma unroll
                for (int ox = 0; ox < 2; ox++)
                    acc[j][oy*2+ox] +=
                        p[oy+0][ox+0]*w0 + p[oy+0][ox+1]*w1 + p[oy+0][ox+2]*w2 +
                        p[oy+1][ox+0]*w3 + p[oy+1][ox+1]*w4 + p[oy+1][ox+2]*w5 +
                        p[oy+2][ox+0]*w6 + p[oy+2][ox+1]*w7 + p[oy+2][ox+2]*w8;
        }
    }

    us8 v0, v1;
    #pragma unroll
    for (int j = 0; j < 16; j++) {
        float m = fmaxf(fmaxf(acc[j][0], acc[j][1]), fmaxf(acc[j][2], acc[j][3]));
        unsigned short u = f2bf(fmaxf(m + bias[co0+j], 0.f));
        if (j < 8) v0[j] = u; else v1[j-8] = u;
    }
    int oy = (ty0+py0) >> 1, ox = (tx0+px0) >> 1;
    unsigned short* o = &out[((size_t)(img*32+oy)*32 + ox)*64 + co0];
    *(us8*)(o)     = v0;
    *(us8*)(o + 8) = v1;
}

// ---------------------------------------------------------------------------
// Weight prepack: fp32 [CO][CI][3][3] -> bf16 [tap][ci/32][co][32]
// ---------------------------------------------------------------------------
struct PPAll {
    const float* src[7];
    unsigned long long dstoff[7];   // ushort offset into Wp
    int cin[7];
    int cout[7];
    int end[7];                     // cumulative (co,ci)-pair end
};

__global__ __launch_bounds__(256)
void prepack(PPAll a, unsigned short* __restrict__ wpbase)
{
    int t = blockIdx.x*256 + threadIdx.x;
    if (t >= 1024000) return;
    int l = 0;
    while (t >= a.end[l]) l++;
    int start = (l == 0) ? 0 : a.end[l-1];
    int local = t - start;
    int cin = a.cin[l], cout = a.cout[l];
    int co = local / cin, ci = local % cin;
    const float* s = a.src[l] + (size_t)local * 9;
    unsigned short* d = wpbase + a.dstoff[l];
    int kct = cin >> 5;
    #pragma unroll
    for (int k = 0; k < 9; k++)
        d[((size_t)(k*kct + (ci >> 5))*cout + co)*32 + (ci & 31)] = f2bf(s[k]);
}

// ---------------------------------------------------------------------------
// MFMA conv: implicit GEMM per tap. Input NHWC bf16, weights prepacked.
// Block = 4 waves = CW co-groups x SW spatial regions. Wave tile M=64 x N=64.
// P==1: region = 8x8 pixels of one image; P==4: region = 4 whole 4x4 images.
// KS>1: fp32 partials [KS][B*H*H][COUT], no bias/relu (combine finishes).
// ---------------------------------------------------------------------------
template<int CIN, int COUT, int H, int CW, int SW, int P, int KS, bool POOL>
__global__ __launch_bounds__(256)
void conv_mfma(const unsigned short* __restrict__ in, const unsigned short* __restrict__ wp,
               const float* __restrict__ bias, void* __restrict__ outp)
{
    constexpr int RY  = (P == 1) ? 8 : 4;
    constexpr int HY  = RY + 2, HX = RY + 2;
    constexpr int KCT = CIN / 32;
    constexpr int KC  = KCT / KS;
    constexpr int REG = (P == 1) ? (H/8)*(H/8) : 1;
    constexpr int LP  = 40;   // pixel stride in ushorts (80 B: spreads all 32 banks)
    static_assert(CW * SW == 4, "4 waves");

    __shared__ unsigned short ins[SW][P][HY][HX][LP];

    const int tid  = threadIdx.x;
    const int lane = tid & 63;
    const int wv   = __builtin_amdgcn_readfirstlane(tid >> 6);
    const int quad = lane >> 4;
    const int nn   = lane & 15;
    const int cg   = wv % CW;
    const int sg   = wv / CW;
    const int co0  = (blockIdx.y * CW + cg) * 64;
    const int ks   = (KS > 1) ? (int)blockIdx.z : 0;

    auto decode = [&](int rg, int& img, int& y0, int& x0) {
        if constexpr (P == 1) {
            img = rg / REG;
            int rs = rg % REG;
            constexpr int RXN = (P == 1) ? (H/8) : 1;
            y0 = (rs / RXN) * 8;
            x0 = (rs % RXN) * 8;
        } else {
            img = rg * 4; y0 = 0; x0 = 0;
        }
    };

    int w_img, w_y0, w_x0;
    decode(blockIdx.x * SW + sg, w_img, w_y0, w_x0);

    fx4 acc[4][4];
    #pragma unroll
    for (int mf = 0; mf < 4; mf++)
        #pragma unroll
        for (int nf = 0; nf < 4; nf++) {
            fx4 z = {0.f, 0.f, 0.f, 0.f};
            acc[mf][nf] = z;
        }

    #pragma unroll 1
    for (int kc = 0; kc < KC; kc++) {
        const int ci0 = (ks*KC + kc) * 32;
        __syncthreads();
        constexpr int U = SW*P*HY*HX*4;
        for (int u = tid; u < U; u += 256) {
            int q   = u & 3;
            int pix = u >> 2;
            int xx  = pix % HX;
            int yy  = (pix / HX) % HY;
            int pp  = (pix / (HX*HY)) % P;
            int ss  = pix / (HX*HY*P);
            int s_img, s_y0, s_x0;
            decode(blockIdx.x * SW + ss, s_img, s_y0, s_x0);
            int gy = s_y0 + yy - 1, gx = s_x0 + xx - 1;
            int imgp = s_img + ((P == 1) ? 0 : pp);
            us8 v;
            #pragma unroll
            for (int e = 0; e < 8; e++) v[e] = 0;
            if (gy >= 0 && gy < H && gx >= 0 && gx < H)
                v = *(const us8*)&in[(((size_t)imgp*H + gy)*H + gx)*CIN + ci0 + q*8];
            *(us8*)&ins[ss][pp][yy][xx][q*8] = v;
        }
        __syncthreads();

        for (int tap = 0; tap < 9; tap++) {
            const int dy = tap / 3, dx = tap % 3;
            const unsigned short* wb =
                wp + ((size_t)(tap*KCT + ks*KC + kc)*COUT + co0 + nn)*32 + quad*8;
            short8 a[4];
            #pragma unroll
            for (int mf = 0; mf < 4; mf++)
                a[mf] = *(const short8*)(wb + (size_t)mf*16*32);
            short8 b[4];
            #pragma unroll
            for (int nf = 0; nf < 4; nf++) {
                int pp, py, px;
                if constexpr (P == 1) { pp = 0;  py = (nf>>1)*4 + (nn>>2); px = (nf&1)*4 + (nn&3); }
                else                  { pp = nf; py = (nn>>2);             px = (nn&3); }
                b[nf] = *(const short8*)&ins[sg][pp][py+dy][px+dx][quad*8];
            }
            #pragma unroll
            for (int mf = 0; mf < 4; mf++)
                #pragma unroll
                for (int nf = 0; nf < 4; nf++)
                    acc[mf][nf] = __builtin_amdgcn_mfma_f32_16x16x32_bf16(
                        a[mf], b[nf], acc[mf][nf], 0, 0, 0);
        }
    }

    if constexpr (KS > 1) {
        float* part = (float*)outp;
        constexpr size_t NPIX = (size_t)BATCH * H * H;
        #pragma unroll
        for (int mf = 0; mf < 4; mf++)
            #pragma unroll
            for (int nf = 0; nf < 4; nf++) {
                int img, py, px;
                if constexpr (P == 1) { img = w_img;      py = w_y0 + (nf>>1)*4 + (nn>>2); px = w_x0 + (nf&1)*4 + (nn&3); }
                else                  { img = w_img + nf; py = (nn>>2);                    px = (nn&3); }
                size_t npix = (size_t)img*H*H + py*H + px;
                size_t idx  = ((size_t)ks*NPIX + npix)*COUT + co0 + mf*16 + quad*4;
                *(fx4*)&part[idx] = acc[mf][nf];
            }
    } else if constexpr (POOL) {
        unsigned short* out = (unsigned short*)outp;
        constexpr int HO = H/2;
        #pragma unroll
        for (int mf = 0; mf < 4; mf++) {
            fx4 b4 = *(const fx4*)&bias[co0 + mf*16 + quad*4];
            #pragma unroll
            for (int nf = 0; nf < 4; nf++) {
                us4 o;
                #pragma unroll
                for (int r = 0; r < 4; r++) {
                    float v = acc[mf][nf][r];
                    v = fmaxf(v, __shfl_xor(v, 1));
                    v = fmaxf(v, __shfl_xor(v, 4));
                    o[r] = f2bf(fmaxf(v + b4[r], 0.f));
                }
                if ((nn & 5) == 0) {
                    int py = w_y0 + (nf>>1)*4 + (nn>>2);
                    int px = w_x0 + (nf&1)*4 + (nn&3);
                    size_t idx = (((size_t)w_img*HO + (py>>1))*HO + (px>>1))*COUT
                               + co0 + mf*16 + quad*4;
                    *(us4*)&out[idx] = o;
                }
            }
        }
    } else {
        unsigned short* out = (unsigned short*)outp;
        #pragma unroll
        for (int mf = 0; mf < 4; mf++) {
            fx4 b4 = *(const fx4*)&bias[co0 + mf*16 + quad*4];
            #pragma unroll
            for (int nf = 0; nf < 4; nf++) {
                us4 o;
                #pragma unroll
                for (int r = 0; r < 4; r++)
                    o[r] = f2bf(fmaxf(acc[mf][nf][r] + b4[r], 0.f));
                int py = w_y0 + (nf>>1)*4 + (nn>>2);
                int px = w_x0 + (nf&1)*4 + (nn&3);
                size_t idx = (((size_t)w_img*H + py)*H + px)*COUT + co0 + mf*16 + quad*4;
                *(us4*)&out[idx] = o;
            }
        }
    }
}

// ---------------------------------------------------------------------------
// Combine kernels for K-split partials
// ---------------------------------------------------------------------------
template<int KS, int NPIX, int CO>
__global__ __launch_bounds__(256)
void combine_nhwc(const float* __restrict__ part, const float* __restrict__ bias,
                  unsigned short* __restrict__ out)
{
    constexpr int C4 = CO/4;
    int t = blockIdx.x*256 + threadIdx.x;
    if (t >= NPIX*C4) return;
    int c4 = t % C4, pix = t / C4;
    fx4 s = *(const fx4*)&bias[c4*4];
    #pragma unroll
    for (int k = 0; k < KS; k++)
        s += *(const fx4*)&part[((size_t)k*NPIX + pix)*CO + c4*4];
    us4 o;
    #pragma unroll
    for (int r = 0; r < 4; r++) o[r] = f2bf(fmaxf(s[r], 0.f));
    *(us4*)&out[(size_t)pix*CO + c4*4] = o;
}

template<int KS, int HI, int CO>
__global__ __launch_bounds__(256)
void combine_pool(const float* __restrict__ part, const float* __restrict__ bias,
                  unsigned short* __restrict__ out)
{
    constexpr int HO = HI/2, C4 = CO/4;
    constexpr size_t NPIX = (size_t)BATCH*HI*HI;
    int t = blockIdx.x*256 + threadIdx.x;
    if (t >= BATCH*HO*HO*C4) return;
    int c4 = t % C4;
    int r  = t / C4;
    int xo = r % HO, yo = (r/HO) % HO, img = r/(HO*HO);
    fx4 m = {-1e30f, -1e30f, -1e30f, -1e30f};
    #pragma unroll
    for (int iy = 0; iy < 2; iy++)
        #pragma unroll
        for (int ix = 0; ix < 2; ix++) {
            size_t pix = (size_t)img*HI*HI + (2*yo+iy)*HI + (2*xo+ix);
            fx4 s = {0.f,0.f,0.f,0.f};
            #pragma unroll
            for (int k = 0; k < KS; k++)
                s += *(const fx4*)&part[((size_t)k*NPIX + pix)*CO + c4*4];
            #pragma unroll
            for (int e = 0; e < 4; e++) m[e] = fmaxf(m[e], s[e]);
        }
    fx4 b4 = *(const fx4*)&bias[c4*4];
    us4 o;
    #pragma unroll
    for (int e = 0; e < 4; e++) o[e] = f2bf(fmaxf(m[e] + b4[e], 0.f));
    *(us4*)&out[((size_t)(img*HO+yo)*HO + xo)*CO + c4*4] = o;
}

// conv4b finish: sum KS=8 partials + bias + relu + engram mask + pool2
// -> X0 transposed [2048][64] fp32 for the FC stack
__global__ __launch_bounds__(256)
void combine4b(const float* __restrict__ part, const float* __restrict__ bias,
               const float* __restrict__ mask, float* __restrict__ X0)
{
    int t = blockIdx.x*256 + threadIdx.x;
    if (t >= BATCH*512) return;
    int b = t / 512, c = t % 512;
    float s[16];
    #pragma unroll
    for (int p = 0; p < 16; p++) s[p] = 0.f;
    #pragma unroll
    for (int k = 0; k < 8; k++)
        #pragma unroll
        for (int p = 0; p < 16; p++)
            s[p] += part[((size_t)k*1024 + b*16 + p)*512 + c];
    float mk = mask[b*512 + c], bb = bias[c];
    #pragma unroll
    for (int py = 0; py < 2; py++)
        #pragma unroll
        for (int px = 0; px < 2; px++) {
            float m = fmaxf(fmaxf(s[(2*py)*4 + 2*px],     s[(2*py)*4 + 2*px+1]),
                            fmaxf(s[(2*py+1)*4 + 2*px],   s[(2*py+1)*4 + 2*px+1]));
            X0[(size_t)(c*4 + py*2 + px)*64 + b] = mk * fmaxf(m + bb, 0.f);
        }
}

// ---------------------------------------------------------------------------
// engram mask
// ---------------------------------------------------------------------------
__global__ void build_mask(const int* __restrict__ y, const int* __restrict__ btab,
                           float* __restrict__ mask)
{
    __shared__ float m[512];
    int b = blockIdx.x;
    int t = threadIdx.x;               // 128 threads
    for (int i = t; i < 512; i += 128) m[i] = 0.f;
    __syncthreads();
    int cls = y[b];
    int idx = btab[cls*128 + t];
    m[idx] = 1.0f;
    __syncthreads();
    for (int i = t; i < 512; i += 128) mask[b*512 + i] = m[i];
}

// ---------------------------------------------------------------------------
// FC (fp32): x transposed [K][64], weights scalar-loaded
// ---------------------------------------------------------------------------
template<int K, int N, bool RELU, bool TROUT>
__global__ __launch_bounds__(256)
void fc_kernel(const float* __restrict__ xt, const float* __restrict__ w,
               const float* __restrict__ bias, float* __restrict__ out)
{
    __shared__ float red[4][8][64];
    const int tid  = threadIdx.x;
    const int lane = tid & 63;
    const int wv   = __builtin_amdgcn_readfirstlane(tid >> 6);
    const int cg   = wv >> 1;
    const int kh   = wv & 1;
    const int c0   = blockIdx.x*16 + cg*8;

    const float* wrow[8];
    #pragma unroll
    for (int i = 0; i < 8; i++) {
        int c = c0 + i; if (c > N-1) c = N-1;
        wrow[i] = w + (size_t)c*K;
    }
    float acc[8];
    #pragma unroll
    for (int i = 0; i < 8; i++) acc[i] = 0.f;

    const int k0 = kh*(K/2);
    for (int k = k0; k < k0 + K/2; k += 4) {
        float x0 = xt[(size_t)(k+0)*64 + lane];
        float x1 = xt[(size_t)(k+1)*64 + lane];
        float x2 = xt[(size_t)(k+2)*64 + lane];
        float x3 = xt[(size_t)(k+3)*64 + lane];
        #pragma unroll
        for (int i = 0; i < 8; i++)
            acc[i] += x0*wrow[i][k+0] + x1*wrow[i][k+1] + x2*wrow[i][k+2] + x3*wrow[i][k+3];
    }
    #pragma unroll
    for (int i = 0; i < 8; i++) red[wv][i][lane] = acc[i];
    __syncthreads();
    if (kh == 0) {
        #pragma unroll
        for (int i = 0; i < 8; i++) {
            int c = c0 + i;
            if (c < N) {
                float v = red[wv][i][lane] + red[wv+1][i][lane] + bias[c];
                if (RELU) v = fmaxf(v, 0.f);
                if (TROUT) out[(size_t)c*64 + lane] = v;
                else       out[(size_t)lane*N + c] = v;
            }
        }
    }
}

// ---------------------------------------------------------------------------
extern "C" void kernel_launch(void* const* d_in, const int* in_sizes, int n_in,
                              void* d_out, int out_size, void* d_ws, size_t ws_size,
                              hipStream_t stream)
{
    const float* x    = (const float*)d_in[0];
    const int*   y    = (const int*)  d_in[1];
    const int*   btab = (const int*)  d_in[2];
    const float* cw0  = (const float*)d_in[3];  const float* cb0  = (const float*)d_in[4];
    const float* cw1  = (const float*)d_in[5];  const float* cb1  = (const float*)d_in[6];
    const float* cw2a = (const float*)d_in[7];  const float* cb2a = (const float*)d_in[8];
    const float* cw2b = (const float*)d_in[9];  const float* cb2b = (const float*)d_in[10];
    const float* cw3a = (const float*)d_in[11]; const float* cb3a = (const float*)d_in[12];
    const float* cw3b = (const float*)d_in[13]; const float* cb3b = (const float*)d_in[14];
    const float* cw4a = (const float*)d_in[15]; const float* cb4a = (const float*)d_in[16];
    const float* cw4b = (const float*)d_in[17]; const float* cb4b = (const float*)d_in[18];
    const float* fw1  = (const float*)d_in[19]; const float* fb1  = (const float*)d_in[20];
    const float* fw2  = (const float*)d_in[21]; const float* fb2  = (const float*)d_in[22];
    const float* fw3  = (const float*)d_in[23]; const float* fb3  = (const float*)d_in[24];
    (void)in_sizes; (void)n_in; (void)out_size; (void)ws_size;

    float* ws = (float*)d_ws;
    unsigned short* ActA = (unsigned short*)(ws);             // 2,097,152 f = 4.19M bf16
    unsigned short* ActB = (unsigned short*)(ws + 2097152);   // 1,048,576 f
    float*          Pp   = ws + 3145728;                      // 4,194,304 f partials
    unsigned short* Wp   = (unsigned short*)(ws + 7340032);   // 9,216,000 bf16
    float*          M    = ws + 11948032;                     // 32,768 f
    float*          X0   = M  + 32768;                        // 131,072 f
    float*          X1   = X0 + 131072;                       // 262,144 f
    float*          X2   = X1 + 262144;                       // 262,144 f

    // weight prepack (conv1..conv4b)
    PPAll pa;
    const float* srcs[7] = {cw1, cw2a, cw2b, cw3a, cw3b, cw4a, cw4b};
    const unsigned long long doffs[7] = {0, 73728, 368640, 958464, 2138112, 4497408, 6856704};
    const int cins[7]  = {64, 128, 256, 256, 512, 512, 512};
    const int couts[7] = {128, 256, 256, 512, 512, 512, 512};
    const int ends[7]  = {8192, 40960, 106496, 237568, 499712, 761856, 1024000};
    for (int i = 0; i < 7; i++) {
        pa.src[i] = srcs[i]; pa.dstoff[i] = doffs[i];
        pa.cin[i] = cins[i]; pa.cout[i] = couts[i]; pa.end[i] = ends[i];
    }
    prepack<<<4000, 256, 0, stream>>>(pa, Wp);

    // conv0: x -> ActA [64][32][32][64] bf16 NHWC
    conv0_kernel<<<1024, 256, 0, stream>>>(x, cw0, cb0, ActA);
    // conv1 + relu + pool: -> ActB [64][16][16][128]
    conv_mfma<64,128,32,2,2,1,1,true><<<dim3(512,1,1),256,0,stream>>>(ActA, Wp+0, cb1, ActB);
    // conv2a + relu: -> ActA [64][16][16][256]
    conv_mfma<128,256,16,4,1,1,1,false><<<dim3(256,1,1),256,0,stream>>>(ActB, Wp+73728, cb2a, ActA);
    // conv2b + relu + pool: -> ActB [64][8][8][256]
    conv_mfma<256,256,16,4,1,1,1,true><<<dim3(256,1,1),256,0,stream>>>(ActA, Wp+368640, cb2b, ActB);
    // conv3a (KS=2): partials -> combine -> ActA [64][8][8][512]
    conv_mfma<256,512,8,2,2,1,2,false><<<dim3(32,4,2),256,0,stream>>>(ActB, Wp+958464, cb3a, Pp);
    combine_nhwc<2, 4096, 512><<<2048,256,0,stream>>>(Pp, cb3a, ActA);
    // conv3b (KS=2) + pool in combine: -> ActB [64][4][4][512]
    conv_mfma<512,512,8,2,2,1,2,false><<<dim3(32,4,2),256,0,stream>>>(ActA, Wp+2138112, cb3b, Pp);
    combine_pool<2, 8, 512><<<512,256,0,stream>>>(Pp, cb3b, ActB);
    // conv4a (KS=8): -> ActA [64][4][4][512]
    conv_mfma<512,512,4,2,2,4,8,false><<<dim3(8,4,8),256,0,stream>>>(ActB, Wp+4497408, cb4a, Pp);
    combine_nhwc<8, 1024, 512><<<512,256,0,stream>>>(Pp, cb4a, ActA);
    // engram mask
    build_mask<<<64,128,0,stream>>>(y, btab, M);
    // conv4b (KS=8): combine fuses mask + pool + transpose -> X0 [2048][64]
    conv_mfma<512,512,4,2,2,4,8,false><<<dim3(8,4,8),256,0,stream>>>(ActA, Wp+6856704, cb4b, Pp);
    combine4b<<<128,256,0,stream>>>(Pp, cb4b, M, X0);
    // classifier (fp32)
    fc_kernel<2048,4096,true, true ><<<256,256,0,stream>>>(X0, fw1, fb1, X1);
    fc_kernel<4096,4096,true, true ><<<256,256,0,stream>>>(X1, fw2, fb2, X2);
    fc_kernel<4096,1000,false,false><<<63, 256,0,stream>>>(X2, fw3, fb3, (float*)d_out);
}

// Round 3
// 625.022 us; speedup vs baseline: 4.7076x; 1.8660x over previous
//
#include <hip/hip_runtime.h>
#include <hip/hip_bf16.h>
#include <cstddef>

typedef __attribute__((ext_vector_type(8))) short short8;
typedef __attribute__((ext_vector_type(4))) float fx4;
typedef __attribute__((ext_vector_type(4))) unsigned short us4;
typedef __attribute__((ext_vector_type(8))) unsigned short us8;

constexpr int BATCH = 64;

static __device__ __forceinline__ unsigned short f2bf(float x) {
    __hip_bfloat16 h = __float2bfloat16(x);
    return *reinterpret_cast<unsigned short*>(&h);
}

// ---------------------------------------------------------------------------
// conv0: CIN=3 fp32 VALU conv + relu + pool, emits NHWC bf16 [64][32][32][64]
// ---------------------------------------------------------------------------
__global__ __launch_bounds__(256)
void conv0_kernel(const float* __restrict__ x, const float* __restrict__ w,
                  const float* __restrict__ bias, unsigned short* __restrict__ out)
{
    __shared__ float ins[3][18][19];
    const int tid  = threadIdx.x;
    const int lane = tid & 63;
    const int wv   = __builtin_amdgcn_readfirstlane(tid >> 6);
    const int img  = blockIdx.x >> 4;
    const int tile = blockIdx.x & 15;
    const int ty0  = (tile >> 2) * 16, tx0 = (tile & 3) * 16;
    const int py0  = (lane >> 3) * 2,  px0 = (lane & 7) * 2;
    const int co0  = wv * 16;

    for (int t = tid; t < 3*18*18; t += 256) {
        int xx = t % 18, yy = (t/18) % 18, ci = t/(18*18);
        int gy = ty0 + yy - 1, gx = tx0 + xx - 1;
        float v = 0.f;
        if (gy >= 0 && gy < 64 && gx >= 0 && gx < 64)
            v = x[((img*3 + ci)*64 + gy)*64 + gx];
        ins[ci][yy][xx] = v;
    }
    __syncthreads();

    float acc[16][4];
    #pragma unroll
    for (int j = 0; j < 16; j++)
        #pragma unroll
        for (int r = 0; r < 4; r++) acc[j][r] = 0.f;

    #pragma unroll
    for (int ci = 0; ci < 3; ci++) {
        float p[4][4];
        #pragma unroll
        for (int dy = 0; dy < 4; dy++)
            #pragma unroll
            for (int dx = 0; dx < 4; dx++)
                p[dy][dx] = ins[ci][py0+dy][px0+dx];
        #pragma unroll
        for (int j = 0; j < 16; j++) {
            const float* wp = w + ((co0+j)*3 + ci)*9;
            float w0=wp[0],w1=wp[1],w2=wp[2],w3=wp[3],w4=wp[4],
                  w5=wp[5],w6=wp[6],w7=wp[7],w8=wp[8];
            #pragma unroll
            for (int oy = 0; oy < 2; oy++)
                #pragma unroll
                for (int ox = 0; ox < 2; ox++)
                    acc[j][oy*2+ox] +=
                        p[oy+0][ox+0]*w0 + p[oy+0][ox+1]*w1 + p[oy+0][ox+2]*w2 +
                        p[oy+1][ox+0]*w3 + p[oy+1][ox+1]*w4 + p[oy+1][ox+2]*w5 +
                        p[oy+2][ox+0]*w6 + p[oy+2][ox+1]*w7 + p[oy+2][ox+2]*w8;
        }
    }

    us8 v0, v1;
    #pragma unroll
    for (int j = 0; j < 16; j++) {
        float m = fmaxf(fmaxf(acc[j][0], acc[j][1]), fmaxf(acc[j][2], acc[j][3]));
        unsigned short u = f2bf(fmaxf(m + bias[co0+j], 0.f));
        if (j < 8) v0[j] = u; else v1[j-8] = u;
    }
    int oy = (ty0+py0) >> 1, ox = (tx0+px0) >> 1;
    unsigned short* o = &out[((size_t)(img*32+oy)*32 + ox)*64 + co0];
    *(us8*)(o)     = v0;
    *(us8*)(o + 8) = v1;
}

// ---------------------------------------------------------------------------
// Weight prepack: fp32 [CO][CI][3][3] -> bf16 [tap][ci/32][co][32]
// ---------------------------------------------------------------------------
struct PPAll {
    const float* src[7];
    unsigned long long dstoff[7];   // ushort offset into Wp
    int cin[7];
    int cout[7];
    int end[7];                     // cumulative (co,ci)-pair end
};

__global__ __launch_bounds__(256)
void prepack(PPAll a, unsigned short* __restrict__ wpbase)
{
    int t = blockIdx.x*256 + threadIdx.x;
    if (t >= 1024000) return;
    int l = 0;
    while (t >= a.end[l]) l++;
    int start = (l == 0) ? 0 : a.end[l-1];
    int local = t - start;
    int cin = a.cin[l], cout = a.cout[l];
    int co = local / cin, ci = local % cin;
    const float* s = a.src[l] + (size_t)local * 9;
    unsigned short* d = wpbase + a.dstoff[l];
    int kct = cin >> 5;
    #pragma unroll
    for (int k = 0; k < 9; k++)
        d[((size_t)(k*kct + (ci >> 5))*cout + co)*32 + (ci & 31)] = f2bf(s[k]);
}

// ---------------------------------------------------------------------------
// MFMA conv: implicit GEMM per tap. Input NHWC bf16, weights prepacked.
// ---------------------------------------------------------------------------
template<int CIN, int COUT, int H, int CW, int SW, int P, int KS, bool POOL>
__global__ __launch_bounds__(256)
void conv_mfma(const unsigned short* __restrict__ in, const unsigned short* __restrict__ wp,
               const float* __restrict__ bias, void* __restrict__ outp)
{
    constexpr int RY  = (P == 1) ? 8 : 4;
    constexpr int HY  = RY + 2, HX = RY + 2;
    constexpr int KCT = CIN / 32;
    constexpr int KC  = KCT / KS;
    constexpr int REG = (P == 1) ? (H/8)*(H/8) : 1;
    constexpr int LP  = 40;   // pixel stride in ushorts (80 B: spreads all 32 banks)
    static_assert(CW * SW == 4, "4 waves");

    __shared__ unsigned short ins[SW][P][HY][HX][LP];

    const int tid  = threadIdx.x;
    const int lane = tid & 63;
    const int wv   = __builtin_amdgcn_readfirstlane(tid >> 6);
    const int quad = lane >> 4;
    const int nn   = lane & 15;
    const int cg   = wv % CW;
    const int sg   = wv / CW;
    const int co0  = (blockIdx.y * CW + cg) * 64;
    const int ks   = (KS > 1) ? (int)blockIdx.z : 0;

    auto decode = [&](int rg, int& img, int& y0, int& x0) {
        if constexpr (P == 1) {
            img = rg / REG;
            int rs = rg % REG;
            constexpr int RXN = (P == 1) ? (H/8) : 1;
            y0 = (rs / RXN) * 8;
            x0 = (rs % RXN) * 8;
        } else {
            img = rg * 4; y0 = 0; x0 = 0;
        }
    };

    int w_img, w_y0, w_x0;
    decode(blockIdx.x * SW + sg, w_img, w_y0, w_x0);

    fx4 acc[4][4];
    #pragma unroll
    for (int mf = 0; mf < 4; mf++)
        #pragma unroll
        for (int nf = 0; nf < 4; nf++) {
            fx4 z = {0.f, 0.f, 0.f, 0.f};
            acc[mf][nf] = z;
        }

    #pragma unroll 1
    for (int kc = 0; kc < KC; kc++) {
        const int ci0 = (ks*KC + kc) * 32;
        __syncthreads();
        constexpr int U = SW*P*HY*HX*4;
        for (int u = tid; u < U; u += 256) {
            int q   = u & 3;
            int pix = u >> 2;
            int xx  = pix % HX;
            int yy  = (pix / HX) % HY;
            int pp  = (pix / (HX*HY)) % P;
            int ss  = pix / (HX*HY*P);
            int s_img, s_y0, s_x0;
            decode(blockIdx.x * SW + ss, s_img, s_y0, s_x0);
            int gy = s_y0 + yy - 1, gx = s_x0 + xx - 1;
            int imgp = s_img + ((P == 1) ? 0 : pp);
            us8 v;
            #pragma unroll
            for (int e = 0; e < 8; e++) v[e] = 0;
            if (gy >= 0 && gy < H && gx >= 0 && gx < H)
                v = *(const us8*)&in[(((size_t)imgp*H + gy)*H + gx)*CIN + ci0 + q*8];
            *(us8*)&ins[ss][pp][yy][xx][q*8] = v;
        }
        __syncthreads();

        for (int tap = 0; tap < 9; tap++) {
            const int dy = tap / 3, dx = tap % 3;
            const unsigned short* wb =
                wp + ((size_t)(tap*KCT + ks*KC + kc)*COUT + co0 + nn)*32 + quad*8;
            short8 a[4];
            #pragma unroll
            for (int mf = 0; mf < 4; mf++)
                a[mf] = *(const short8*)(wb + (size_t)mf*16*32);
            short8 b[4];
            #pragma unroll
            for (int nf = 0; nf < 4; nf++) {
                int pp, py, px;
                if constexpr (P == 1) { pp = 0;  py = (nf>>1)*4 + (nn>>2); px = (nf&1)*4 + (nn&3); }
                else                  { pp = nf; py = (nn>>2);             px = (nn&3); }
                b[nf] = *(const short8*)&ins[sg][pp][py+dy][px+dx][quad*8];
            }
            #pragma unroll
            for (int mf = 0; mf < 4; mf++)
                #pragma unroll
                for (int nf = 0; nf < 4; nf++)
                    acc[mf][nf] = __builtin_amdgcn_mfma_f32_16x16x32_bf16(
                        a[mf], b[nf], acc[mf][nf], 0, 0, 0);
        }
    }

    if constexpr (KS > 1) {
        float* part = (float*)outp;
        constexpr size_t NPIX = (size_t)BATCH * H * H;
        #pragma unroll
        for (int mf = 0; mf < 4; mf++)
            #pragma unroll
            for (int nf = 0; nf < 4; nf++) {
                int img, py, px;
                if constexpr (P == 1) { img = w_img;      py = w_y0 + (nf>>1)*4 + (nn>>2); px = w_x0 + (nf&1)*4 + (nn&3); }
                else                  { img = w_img + nf; py = (nn>>2);                    px = (nn&3); }
                size_t npix = (size_t)img*H*H + py*H + px;
                size_t idx  = ((size_t)ks*NPIX + npix)*COUT + co0 + mf*16 + quad*4;
                *(fx4*)&part[idx] = acc[mf][nf];
            }
    } else if constexpr (POOL) {
        unsigned short* out = (unsigned short*)outp;
        constexpr int HO = H/2;
        #pragma unroll
        for (int mf = 0; mf < 4; mf++) {
            fx4 b4 = *(const fx4*)&bias[co0 + mf*16 + quad*4];
            #pragma unroll
            for (int nf = 0; nf < 4; nf++) {
                us4 o;
                #pragma unroll
                for (int r = 0; r < 4; r++) {
                    float v = acc[mf][nf][r];
                    v = fmaxf(v, __shfl_xor(v, 1));
                    v = fmaxf(v, __shfl_xor(v, 4));
                    o[r] = f2bf(fmaxf(v + b4[r], 0.f));
                }
                if ((nn & 5) == 0) {
                    int py = w_y0 + (nf>>1)*4 + (nn>>2);
                    int px = w_x0 + (nf&1)*4 + (nn&3);
                    size_t idx = (((size_t)w_img*HO + (py>>1))*HO + (px>>1))*COUT
                               + co0 + mf*16 + quad*4;
                    *(us4*)&out[idx] = o;
                }
            }
        }
    } else {
        unsigned short* out = (unsigned short*)outp;
        #pragma unroll
        for (int mf = 0; mf < 4; mf++) {
            fx4 b4 = *(const fx4*)&bias[co0 + mf*16 + quad*4];
            #pragma unroll
            for (int nf = 0; nf < 4; nf++) {
                us4 o;
                #pragma unroll
                for (int r = 0; r < 4; r++)
                    o[r] = f2bf(fmaxf(acc[mf][nf][r] + b4[r], 0.f));
                int py = w_y0 + (nf>>1)*4 + (nn>>2);
                int px = w_x0 + (nf&1)*4 + (nn&3);
                size_t idx = (((size_t)w_img*H + py)*H + px)*COUT + co0 + mf*16 + quad*4;
                *(us4*)&out[idx] = o;
            }
        }
    }
}

// ---------------------------------------------------------------------------
// Combine kernels for conv K-split partials
// ---------------------------------------------------------------------------
template<int KS, int NPIX, int CO>
__global__ __launch_bounds__(256)
void combine_nhwc(const float* __restrict__ part, const float* __restrict__ bias,
                  unsigned short* __restrict__ out)
{
    constexpr int C4 = CO/4;
    int t = blockIdx.x*256 + threadIdx.x;
    if (t >= NPIX*C4) return;
    int c4 = t % C4, pix = t / C4;
    fx4 s = *(const fx4*)&bias[c4*4];
    #pragma unroll
    for (int k = 0; k < KS; k++)
        s += *(const fx4*)&part[((size_t)k*NPIX + pix)*CO + c4*4];
    us4 o;
    #pragma unroll
    for (int r = 0; r < 4; r++) o[r] = f2bf(fmaxf(s[r], 0.f));
    *(us4*)&out[(size_t)pix*CO + c4*4] = o;
}

template<int KS, int HI, int CO>
__global__ __launch_bounds__(256)
void combine_pool(const float* __restrict__ part, const float* __restrict__ bias,
                  unsigned short* __restrict__ out)
{
    constexpr int HO = HI/2, C4 = CO/4;
    constexpr size_t NPIX = (size_t)BATCH*HI*HI;
    int t = blockIdx.x*256 + threadIdx.x;
    if (t >= BATCH*HO*HO*C4) return;
    int c4 = t % C4;
    int r  = t / C4;
    int xo = r % HO, yo = (r/HO) % HO, img = r/(HO*HO);
    fx4 m = {-1e30f, -1e30f, -1e30f, -1e30f};
    #pragma unroll
    for (int iy = 0; iy < 2; iy++)
        #pragma unroll
        for (int ix = 0; ix < 2; ix++) {
            size_t pix = (size_t)img*HI*HI + (2*yo+iy)*HI + (2*xo+ix);
            fx4 s = {0.f,0.f,0.f,0.f};
            #pragma unroll
            for (int k = 0; k < KS; k++)
                s += *(const fx4*)&part[((size_t)k*NPIX + pix)*CO + c4*4];
            #pragma unroll
            for (int e = 0; e < 4; e++) m[e] = fmaxf(m[e], s[e]);
        }
    fx4 b4 = *(const fx4*)&bias[c4*4];
    us4 o;
    #pragma unroll
    for (int e = 0; e < 4; e++) o[e] = f2bf(fmaxf(m[e] + b4[e], 0.f));
    *(us4*)&out[((size_t)(img*HO+yo)*HO + xo)*CO + c4*4] = o;
}

// conv4b finish: sum KS=8 partials + bias + relu + engram mask + pool2
// -> X0 bf16 row-major [64][2048] for the MFMA FC stack
__global__ __launch_bounds__(256)
void combine4b(const float* __restrict__ part, const float* __restrict__ bias,
               const float* __restrict__ mask, unsigned short* __restrict__ X0)
{
    int t = blockIdx.x*256 + threadIdx.x;
    if (t >= BATCH*512) return;
    int b = t / 512, c = t % 512;
    float s[16];
    #pragma unroll
    for (int p = 0; p < 16; p++) s[p] = 0.f;
    #pragma unroll
    for (int k = 0; k < 8; k++)
        #pragma unroll
        for (int p = 0; p < 16; p++)
            s[p] += part[((size_t)k*1024 + b*16 + p)*512 + c];
    float mk = mask[b*512 + c], bb = bias[c];
    us4 o;
    #pragma unroll
    for (int py = 0; py < 2; py++)
        #pragma unroll
        for (int px = 0; px < 2; px++) {
            float m = fmaxf(fmaxf(s[(2*py)*4 + 2*px],     s[(2*py)*4 + 2*px+1]),
                            fmaxf(s[(2*py+1)*4 + 2*px],   s[(2*py+1)*4 + 2*px+1]));
            o[py*2+px] = f2bf(mk * fmaxf(m + bb, 0.f));
        }
    *(us4*)&X0[(size_t)b*2048 + c*4] = o;
}

// ---------------------------------------------------------------------------
// engram mask
// ---------------------------------------------------------------------------
__global__ void build_mask(const int* __restrict__ y, const int* __restrict__ btab,
                           float* __restrict__ mask)
{
    __shared__ float m[512];
    int b = blockIdx.x;
    int t = threadIdx.x;               // 128 threads
    for (int i = t; i < 512; i += 128) m[i] = 0.f;
    __syncthreads();
    int cls = y[b];
    int idx = btab[cls*128 + t];
    m[idx] = 1.0f;
    __syncthreads();
    for (int i = t; i < 512; i += 128) mask[b*512 + i] = m[i];
}

// ---------------------------------------------------------------------------
// MFMA FC: C[64,N] = X[64,K](bf16) @ W[N,K]^T(fp32, cvt in-register).
// Block = 4 waves, all on the same 64-column group, each owning a K-subslice.
// Wave k-loop: stage own X[64][32] slice in private LDS tile; W streamed as
// 2x float4/lane per 16-col fragment (coalesced); cross-wave LDS reduce;
// fp32 partials P[KSO][64][NP]; combine kernel applies bias/relu/cast.
// ---------------------------------------------------------------------------
template<int K, int NP, int NREAL, int KSO>
__global__ __launch_bounds__(256)
void fc_mfma(const unsigned short* __restrict__ X, const float* __restrict__ W,
             float* __restrict__ P)
{
    constexpr int KW = K / (KSO*4);   // per-wave K extent
    constexpr int NI = KW / 32;       // k-iterations
    __shared__ alignas(16) unsigned short XL[4][64][40];
    __shared__ alignas(16) float R[64][68];

    const int tid  = threadIdx.x;
    const int lane = tid & 63;
    const int wv   = __builtin_amdgcn_readfirstlane(tid >> 6);
    const int quad = lane >> 4;
    const int nn   = lane & 15;
    const int c0   = blockIdx.x * 64;
    const int ksb  = blockIdx.y;
    const int k0   = (ksb*4 + wv) * KW;

    fx4 acc[4][4];
    #pragma unroll
    for (int mf = 0; mf < 4; mf++)
        #pragma unroll
        for (int nf = 0; nf < 4; nf++) {
            fx4 z = {0.f,0.f,0.f,0.f};
            acc[mf][nf] = z;
        }

    #pragma unroll
    for (int kc = 0; kc < NI; kc++) {
        const int kw = k0 + kc*32;
        // stage X rows (lane = batch row), 64 B contiguous per lane
        const unsigned short* xp = X + (size_t)lane*K + kw;
        us8 x0 = *(const us8*)(xp);
        us8 x1 = *(const us8*)(xp + 8);
        us8 x2 = *(const us8*)(xp + 16);
        us8 x3 = *(const us8*)(xp + 24);
        *(us8*)&XL[wv][lane][0]  = x0;
        *(us8*)&XL[wv][lane][8]  = x1;
        *(us8*)&XL[wv][lane][16] = x2;
        *(us8*)&XL[wv][lane][24] = x3;
        // B fragments: W fp32 -> bf16
        short8 b[4];
        #pragma unroll
        for (int nf = 0; nf < 4; nf++) {
            int c = c0 + nf*16 + nn;
            if (c > NREAL-1) c = NREAL-1;
            const float* wp = W + (size_t)c*K + kw + quad*8;
            float4 f0 = *(const float4*)(wp);
            float4 f1 = *(const float4*)(wp + 4);
            short8 t;
            t[0] = (short)f2bf(f0.x); t[1] = (short)f2bf(f0.y);
            t[2] = (short)f2bf(f0.z); t[3] = (short)f2bf(f0.w);
            t[4] = (short)f2bf(f1.x); t[5] = (short)f2bf(f1.y);
            t[6] = (short)f2bf(f1.z); t[7] = (short)f2bf(f1.w);
            b[nf] = t;
        }
        // A fragments from LDS (row = mf*16+nn, 16B contiguous)
        short8 a[4];
        #pragma unroll
        for (int mf = 0; mf < 4; mf++)
            a[mf] = *(const short8*)&XL[wv][mf*16 + nn][quad*8];
        #pragma unroll
        for (int mf = 0; mf < 4; mf++)
            #pragma unroll
            for (int nf = 0; nf < 4; nf++)
                acc[mf][nf] = __builtin_amdgcn_mfma_f32_16x16x32_bf16(
                    a[mf], b[nf], acc[mf][nf], 0, 0, 0);
    }

    // cross-wave reduce (sequential RMW; 2-way bank alias only)
    for (int ww = 0; ww < 4; ww++) {
        __syncthreads();
        if (wv == ww) {
            #pragma unroll
            for (int mf = 0; mf < 4; mf++)
                #pragma unroll
                for (int nf = 0; nf < 4; nf++) {
                    int n = nf*16 + nn;
                    #pragma unroll
                    for (int r = 0; r < 4; r++) {
                        int m = mf*16 + quad*4 + r;
                        float v = acc[mf][nf][r];
                        if (ww) v += R[m][n];
                        R[m][n] = v;
                    }
                }
        }
    }
    __syncthreads();
    // cooperative coalesced store of the 64x64 fp32 tile
    {
        int m  = tid >> 2;
        int n0 = (tid & 3) * 16;
        float* dst = P + ((size_t)ksb*64 + m)*NP + c0 + n0;
        #pragma unroll
        for (int j = 0; j < 4; j++) {
            fx4 v = *(const fx4*)&R[m][n0 + j*4];
            *(fx4*)(dst + j*4) = v;
        }
    }
}

template<int N, int KS>
__global__ __launch_bounds__(256)
void fc_combine_bf16(const float* __restrict__ P, const float* __restrict__ bias,
                     unsigned short* __restrict__ Xo)
{
    int t = blockIdx.x*256 + threadIdx.x;
    if (t >= 64*(N/4)) return;
    int c4 = t % (N/4);
    int b  = t / (N/4);
    fx4 s = *(const fx4*)&bias[c4*4];
    #pragma unroll
    for (int ks = 0; ks < KS; ks++)
        s += *(const fx4*)&P[((size_t)ks*64 + b)*N + c4*4];
    us4 o;
    #pragma unroll
    for (int r = 0; r < 4; r++) o[r] = f2bf(fmaxf(s[r], 0.f));
    *(us4*)&Xo[(size_t)b*N + c4*4] = o;
}

__global__ __launch_bounds__(256)
void fc3_combine(const float* __restrict__ P, const float* __restrict__ bias,
                 float* __restrict__ out)
{
    int t = blockIdx.x*256 + threadIdx.x;
    if (t >= 64*1000) return;
    int b = t / 1000, c = t % 1000;
    float s = bias[c];
    #pragma unroll
    for (int ks = 0; ks < 16; ks++)
        s += P[((size_t)ks*64 + b)*1024 + c];
    out[t] = s;
}

// ---------------------------------------------------------------------------
extern "C" void kernel_launch(void* const* d_in, const int* in_sizes, int n_in,
                              void* d_out, int out_size, void* d_ws, size_t ws_size,
                              hipStream_t stream)
{
    const float* x    = (const float*)d_in[0];
    const int*   y    = (const int*)  d_in[1];
    const int*   btab = (const int*)  d_in[2];
    const float* cw0  = (const float*)d_in[3];  const float* cb0  = (const float*)d_in[4];
    const float* cw1  = (const float*)d_in[5];  const float* cb1  = (const float*)d_in[6];
    const float* cw2a = (const float*)d_in[7];  const float* cb2a = (const float*)d_in[8];
    const float* cw2b = (const float*)d_in[9];  const float* cb2b = (const float*)d_in[10];
    const float* cw3a = (const float*)d_in[11]; const float* cb3a = (const float*)d_in[12];
    const float* cw3b = (const float*)d_in[13]; const float* cb3b = (const float*)d_in[14];
    const float* cw4a = (const float*)d_in[15]; const float* cb4a = (const float*)d_in[16];
    const float* cw4b = (const float*)d_in[17]; const float* cb4b = (const float*)d_in[18];
    const float* fw1  = (const float*)d_in[19]; const float* fb1  = (const float*)d_in[20];
    const float* fw2  = (const float*)d_in[21]; const float* fb2  = (const float*)d_in[22];
    const float* fw3  = (const float*)d_in[23]; const float* fb3  = (const float*)d_in[24];
    (void)in_sizes; (void)n_in; (void)out_size; (void)ws_size;

    float* ws = (float*)d_ws;
    unsigned short* ActA = (unsigned short*)(ws);             // 2,097,152 f
    unsigned short* ActB = (unsigned short*)(ws + 2097152);   // 1,048,576 f
    float*          Pp   = ws + 3145728;                      // 4,194,304 f (conv+fc partials)
    unsigned short* Wp   = (unsigned short*)(ws + 7340032);   // 9,216,000 bf16
    float*          M    = ws + 11948032;                     // 32,768 f
    unsigned short* X0   = (unsigned short*)(ws + 11980800);  // [64][2048] bf16
    unsigned short* X1   = (unsigned short*)(ws + 12046336);  // [64][4096] bf16
    unsigned short* X2   = (unsigned short*)(ws + 12177408);  // [64][4096] bf16

    // weight prepack (conv1..conv4b)
    PPAll pa;
    const float* srcs[7] = {cw1, cw2a, cw2b, cw3a, cw3b, cw4a, cw4b};
    const unsigned long long doffs[7] = {0, 73728, 368640, 958464, 2138112, 4497408, 6856704};
    const int cins[7]  = {64, 128, 256, 256, 512, 512, 512};
    const int couts[7] = {128, 256, 256, 512, 512, 512, 512};
    const int ends[7]  = {8192, 40960, 106496, 237568, 499712, 761856, 1024000};
    for (int i = 0; i < 7; i++) {
        pa.src[i] = srcs[i]; pa.dstoff[i] = doffs[i];
        pa.cin[i] = cins[i]; pa.cout[i] = couts[i]; pa.end[i] = ends[i];
    }
    prepack<<<4000, 256, 0, stream>>>(pa, Wp);

    // conv0: x -> ActA [64][32][32][64] bf16 NHWC
    conv0_kernel<<<1024, 256, 0, stream>>>(x, cw0, cb0, ActA);
    // conv1 + relu + pool: -> ActB [64][16][16][128]
    conv_mfma<64,128,32,2,2,1,1,true><<<dim3(512,1,1),256,0,stream>>>(ActA, Wp+0, cb1, ActB);
    // conv2a + relu: -> ActA [64][16][16][256]
    conv_mfma<128,256,16,4,1,1,1,false><<<dim3(256,1,1),256,0,stream>>>(ActB, Wp+73728, cb2a, ActA);
    // conv2b + relu + pool: -> ActB [64][8][8][256]
    conv_mfma<256,256,16,4,1,1,1,true><<<dim3(256,1,1),256,0,stream>>>(ActA, Wp+368640, cb2b, ActB);
    // conv3a (KS=2): partials -> combine -> ActA [64][8][8][512]
    conv_mfma<256,512,8,2,2,1,2,false><<<dim3(32,4,2),256,0,stream>>>(ActB, Wp+958464, cb3a, Pp);
    combine_nhwc<2, 4096, 512><<<2048,256,0,stream>>>(Pp, cb3a, ActA);
    // conv3b (KS=2) + pool in combine: -> ActB [64][4][4][512]
    conv_mfma<512,512,8,2,2,1,2,false><<<dim3(32,4,2),256,0,stream>>>(ActA, Wp+2138112, cb3b, Pp);
    combine_pool<2, 8, 512><<<512,256,0,stream>>>(Pp, cb3b, ActB);
    // conv4a (KS=8): -> ActA [64][4][4][512]
    conv_mfma<512,512,4,2,2,4,8,false><<<dim3(8,4,8),256,0,stream>>>(ActB, Wp+4497408, cb4a, Pp);
    combine_nhwc<8, 1024, 512><<<512,256,0,stream>>>(Pp, cb4a, ActA);
    // engram mask
    build_mask<<<64,128,0,stream>>>(y, btab, M);
    // conv4b (KS=8): combine fuses mask + pool -> X0 [64][2048] bf16
    conv_mfma<512,512,4,2,2,4,8,false><<<dim3(8,4,8),256,0,stream>>>(ActA, Wp+6856704, cb4b, Pp);
    combine4b<<<128,256,0,stream>>>(Pp, cb4b, M, X0);
    // classifier: MFMA GEMMs, weights streamed fp32 -> bf16 in-register
    fc_mfma<2048,4096,4096,4><<<dim3(64,4),256,0,stream>>>(X0, fw1, Pp);
    fc_combine_bf16<4096,4><<<256,256,0,stream>>>(Pp, fb1, X1);
    fc_mfma<4096,4096,4096,8><<<dim3(64,8),256,0,stream>>>(X1, fw2, Pp);
    fc_combine_bf16<4096,8><<<256,256,0,stream>>>(Pp, fb2, X2);
    fc_mfma<4096,1024,1000,16><<<dim3(16,16),256,0,stream>>>(X2, fw3, Pp);
    fc3_combine<<<250,256,0,stream>>>(Pp, fb3, (float*)d_out);
}

// Round 4
// 516.294 us; speedup vs baseline: 5.6990x; 1.2106x over previous
//
#include <hip/hip_runtime.h>
#include <hip/hip_bf16.h>
#include <cstddef>

typedef __attribute__((ext_vector_type(8))) short short8;
typedef __attribute__((ext_vector_type(4))) float fx4;
typedef __attribute__((ext_vector_type(4))) unsigned short us4;
typedef __attribute__((ext_vector_type(8))) unsigned short us8;

constexpr int BATCH = 64;

static __device__ __forceinline__ unsigned short f2bf(float x) {
    __hip_bfloat16 h = __float2bfloat16(x);
    return *reinterpret_cast<unsigned short*>(&h);
}

// ---------------------------------------------------------------------------
// conv0: CIN=3 fp32 VALU conv + relu + pool, emits NHWC bf16 [64][32][32][64]
// ---------------------------------------------------------------------------
__global__ __launch_bounds__(256)
void conv0_kernel(const float* __restrict__ x, const float* __restrict__ w,
                  const float* __restrict__ bias, unsigned short* __restrict__ out)
{
    __shared__ float ins[3][18][19];
    const int tid  = threadIdx.x;
    const int lane = tid & 63;
    const int wv   = __builtin_amdgcn_readfirstlane(tid >> 6);
    const int img  = blockIdx.x >> 4;
    const int tile = blockIdx.x & 15;
    const int ty0  = (tile >> 2) * 16, tx0 = (tile & 3) * 16;
    const int py0  = (lane >> 3) * 2,  px0 = (lane & 7) * 2;
    const int co0  = wv * 16;

    for (int t = tid; t < 3*18*18; t += 256) {
        int xx = t % 18, yy = (t/18) % 18, ci = t/(18*18);
        int gy = ty0 + yy - 1, gx = tx0 + xx - 1;
        float v = 0.f;
        if (gy >= 0 && gy < 64 && gx >= 0 && gx < 64)
            v = x[((img*3 + ci)*64 + gy)*64 + gx];
        ins[ci][yy][xx] = v;
    }
    __syncthreads();

    float acc[16][4];
    #pragma unroll
    for (int j = 0; j < 16; j++)
        #pragma unroll
        for (int r = 0; r < 4; r++) acc[j][r] = 0.f;

    #pragma unroll
    for (int ci = 0; ci < 3; ci++) {
        float p[4][4];
        #pragma unroll
        for (int dy = 0; dy < 4; dy++)
            #pragma unroll
            for (int dx = 0; dx < 4; dx++)
                p[dy][dx] = ins[ci][py0+dy][px0+dx];
        #pragma unroll
        for (int j = 0; j < 16; j++) {
            const float* wp = w + ((co0+j)*3 + ci)*9;
            float w0=wp[0],w1=wp[1],w2=wp[2],w3=wp[3],w4=wp[4],
                  w5=wp[5],w6=wp[6],w7=wp[7],w8=wp[8];
            #pragma unroll
            for (int oy = 0; oy < 2; oy++)
                #pragma unroll
                for (int ox = 0; ox < 2; ox++)
                    acc[j][oy*2+ox] +=
                        p[oy+0][ox+0]*w0 + p[oy+0][ox+1]*w1 + p[oy+0][ox+2]*w2 +
                        p[oy+1][ox+0]*w3 + p[oy+1][ox+1]*w4 + p[oy+1][ox+2]*w5 +
                        p[oy+2][ox+0]*w6 + p[oy+2][ox+1]*w7 + p[oy+2][ox+2]*w8;
        }
    }

    us8 v0, v1;
    #pragma unroll
    for (int j = 0; j < 16; j++) {
        float m = fmaxf(fmaxf(acc[j][0], acc[j][1]), fmaxf(acc[j][2], acc[j][3]));
        unsigned short u = f2bf(fmaxf(m + bias[co0+j], 0.f));
        if (j < 8) v0[j] = u; else v1[j-8] = u;
    }
    int oy = (ty0+py0) >> 1, ox = (tx0+px0) >> 1;
    unsigned short* o = &out[((size_t)(img*32+oy)*32 + ox)*64 + co0];
    *(us8*)(o)     = v0;
    *(us8*)(o + 8) = v1;
}

// ---------------------------------------------------------------------------
// Weight prepack: fp32 [CO][CI][3][3] -> bf16 [tap][ci/32][co][32]
// ---------------------------------------------------------------------------
struct PPAll {
    const float* src[7];
    unsigned long long dstoff[7];
    int cin[7];
    int cout[7];
    int end[7];
};

__global__ __launch_bounds__(256)
void prepack(PPAll a, unsigned short* __restrict__ wpbase)
{
    int t = blockIdx.x*256 + threadIdx.x;
    if (t >= 1024000) return;
    int l = 0;
    while (t >= a.end[l]) l++;
    int start = (l == 0) ? 0 : a.end[l-1];
    int local = t - start;
    int cin = a.cin[l], cout = a.cout[l];
    int co = local / cin, ci = local % cin;
    const float* s = a.src[l] + (size_t)local * 9;
    unsigned short* d = wpbase + a.dstoff[l];
    int kct = cin >> 5;
    #pragma unroll
    for (int k = 0; k < 9; k++)
        d[((size_t)(k*kct + (ci >> 5))*cout + co)*32 + (ci & 31)] = f2bf(s[k]);
}

// ---------------------------------------------------------------------------
// MFMA conv: implicit GEMM per tap. Input NHWC bf16, weights prepacked.
// Round-4 structure: stage the FULL CIN/KS channel slice once (one barrier),
// then a barrier-free KC x 9-tap MFMA loop (compiler pipelines loads).
// Grid >= 512 blocks everywhere via KS splits -> 2 blocks/CU resident.
// ---------------------------------------------------------------------------
template<int CIN, int COUT, int H, int CW, int SW, int P, int KS, bool POOL>
__global__ __launch_bounds__(256, 2)
void conv_mfma(const unsigned short* __restrict__ in, const unsigned short* __restrict__ wp,
               const float* __restrict__ bias, void* __restrict__ outp)
{
    constexpr int RY   = (P == 1) ? 8 : 4;
    constexpr int HY   = RY + 2, HX = RY + 2;
    constexpr int KCT  = CIN / 32;      // total 32-ch chunks
    constexpr int CINS = CIN / KS;      // channels staged per block
    constexpr int KC   = CINS / 32;     // staged chunks
    constexpr int PADW = (CINS == 128) ? 24 : 8;   // bank-spread pixel padding
    constexpr int STR  = CINS + PADW;   // ushort stride per pixel
    constexpr int REG  = (P == 1) ? (H/8)*(H/8) : 1;
    static_assert(CW * SW == 4, "4 waves");

    __shared__ unsigned short ins[SW][P][HY][HX][STR];

    const int tid  = threadIdx.x;
    const int lane = tid & 63;
    const int wv   = __builtin_amdgcn_readfirstlane(tid >> 6);
    const int quad = lane >> 4;
    const int nn   = lane & 15;
    const int cg   = wv % CW;
    const int sg   = wv / CW;
    const int co0  = (blockIdx.y * CW + cg) * 64;
    const int ks   = (KS > 1) ? (int)blockIdx.z : 0;

    auto decode = [&](int rg, int& img, int& y0, int& x0) {
        if constexpr (P == 1) {
            img = rg / REG;
            int rs = rg % REG;
            constexpr int RXN = (P == 1) ? (H/8) : 1;
            y0 = (rs / RXN) * 8;
            x0 = (rs % RXN) * 8;
        } else {
            img = rg * 4; y0 = 0; x0 = 0;
        }
    };

    int w_img, w_y0, w_x0;
    decode(blockIdx.x * SW + sg, w_img, w_y0, w_x0);

    // ---- stage all CINS channels of the tile(s), one barrier ----
    {
        constexpr int E = SW*P*HY*HX*(CINS/8);
        for (int u = tid; u < E; u += 256) {
            int q   = u % (CINS/8);
            int pix = u / (CINS/8);
            int xx  = pix % HX;
            int yy  = (pix / HX) % HY;
            int pp  = (pix / (HX*HY)) % P;
            int ss  = pix / (HX*HY*P);
            int s_img, s_y0, s_x0;
            decode(blockIdx.x * SW + ss, s_img, s_y0, s_x0);
            int gy = s_y0 + yy - 1, gx = s_x0 + xx - 1;
            int imgp = s_img + ((P == 1) ? 0 : pp);
            us8 v;
            #pragma unroll
            for (int e = 0; e < 8; e++) v[e] = 0;
            if (gy >= 0 && gy < H && gx >= 0 && gx < H)
                v = *(const us8*)&in[(((size_t)imgp*H + gy)*H + gx)*CIN + ks*CINS + q*8];
            *(us8*)&ins[ss][pp][yy][xx][q*8] = v;
        }
    }
    __syncthreads();

    fx4 acc[4][4];
    #pragma unroll
    for (int mf = 0; mf < 4; mf++)
        #pragma unroll
        for (int nf = 0; nf < 4; nf++) {
            fx4 z = {0.f, 0.f, 0.f, 0.f};
            acc[mf][nf] = z;
        }

    // ---- barrier-free MFMA loop ----
    #pragma unroll 1
    for (int kc = 0; kc < KC; kc++) {
        #pragma unroll 3
        for (int tap = 0; tap < 9; tap++) {
            const int dy = tap / 3, dx = tap % 3;
            const unsigned short* wb =
                wp + ((size_t)(tap*KCT + ks*KC + kc)*COUT + co0 + nn)*32 + quad*8;
            short8 a[4];
            #pragma unroll
            for (int mf = 0; mf < 4; mf++)
                a[mf] = *(const short8*)(wb + (size_t)mf*16*32);
            short8 b[4];
            #pragma unroll
            for (int nf = 0; nf < 4; nf++) {
                int pp, py, px;
                if constexpr (P == 1) { pp = 0;  py = (nf>>1)*4 + (nn>>2); px = (nf&1)*4 + (nn&3); }
                else                  { pp = nf; py = (nn>>2);             px = (nn&3); }
                b[nf] = *(const short8*)&ins[sg][pp][py+dy][px+dx][kc*32 + quad*8];
            }
            #pragma unroll
            for (int mf = 0; mf < 4; mf++)
                #pragma unroll
                for (int nf = 0; nf < 4; nf++)
                    acc[mf][nf] = __builtin_amdgcn_mfma_f32_16x16x32_bf16(
                        a[mf], b[nf], acc[mf][nf], 0, 0, 0);
        }
    }

    if constexpr (KS > 1) {
        float* part = (float*)outp;
        constexpr size_t NPIX = (size_t)BATCH * H * H;
        #pragma unroll
        for (int mf = 0; mf < 4; mf++)
            #pragma unroll
            for (int nf = 0; nf < 4; nf++) {
                int img, py, px;
                if constexpr (P == 1) { img = w_img;      py = w_y0 + (nf>>1)*4 + (nn>>2); px = w_x0 + (nf&1)*4 + (nn&3); }
                else                  { img = w_img + nf; py = (nn>>2);                    px = (nn&3); }
                size_t npix = (size_t)img*H*H + py*H + px;
                size_t idx  = ((size_t)ks*NPIX + npix)*COUT + co0 + mf*16 + quad*4;
                *(fx4*)&part[idx] = acc[mf][nf];
            }
    } else if constexpr (POOL) {
        unsigned short* out = (unsigned short*)outp;
        constexpr int HO = H/2;
        #pragma unroll
        for (int mf = 0; mf < 4; mf++) {
            fx4 b4 = *(const fx4*)&bias[co0 + mf*16 + quad*4];
            #pragma unroll
            for (int nf = 0; nf < 4; nf++) {
                us4 o;
                #pragma unroll
                for (int r = 0; r < 4; r++) {
                    float v = acc[mf][nf][r];
                    v = fmaxf(v, __shfl_xor(v, 1));
                    v = fmaxf(v, __shfl_xor(v, 4));
                    o[r] = f2bf(fmaxf(v + b4[r], 0.f));
                }
                if ((nn & 5) == 0) {
                    int py = w_y0 + (nf>>1)*4 + (nn>>2);
                    int px = w_x0 + (nf&1)*4 + (nn&3);
                    size_t idx = (((size_t)w_img*HO + (py>>1))*HO + (px>>1))*COUT
                               + co0 + mf*16 + quad*4;
                    *(us4*)&out[idx] = o;
                }
            }
        }
    } else {
        unsigned short* out = (unsigned short*)outp;
        #pragma unroll
        for (int mf = 0; mf < 4; mf++) {
            fx4 b4 = *(const fx4*)&bias[co0 + mf*16 + quad*4];
            #pragma unroll
            for (int nf = 0; nf < 4; nf++) {
                us4 o;
                #pragma unroll
                for (int r = 0; r < 4; r++)
                    o[r] = f2bf(fmaxf(acc[mf][nf][r] + b4[r], 0.f));
                int py = w_y0 + (nf>>1)*4 + (nn>>2);
                int px = w_x0 + (nf&1)*4 + (nn&3);
                size_t idx = (((size_t)w_img*H + py)*H + px)*COUT + co0 + mf*16 + quad*4;
                *(us4*)&out[idx] = o;
            }
        }
    }
}

// ---------------------------------------------------------------------------
// Combine kernels for conv K-split partials
// ---------------------------------------------------------------------------
template<int KS, int NPIX, int CO>
__global__ __launch_bounds__(256)
void combine_nhwc(const float* __restrict__ part, const float* __restrict__ bias,
                  unsigned short* __restrict__ out)
{
    constexpr int C4 = CO/4;
    int t = blockIdx.x*256 + threadIdx.x;
    if (t >= NPIX*C4) return;
    int c4 = t % C4, pix = t / C4;
    fx4 s = *(const fx4*)&bias[c4*4];
    #pragma unroll
    for (int k = 0; k < KS; k++)
        s += *(const fx4*)&part[((size_t)k*NPIX + pix)*CO + c4*4];
    us4 o;
    #pragma unroll
    for (int r = 0; r < 4; r++) o[r] = f2bf(fmaxf(s[r], 0.f));
    *(us4*)&out[(size_t)pix*CO + c4*4] = o;
}

template<int KS, int HI, int CO>
__global__ __launch_bounds__(256)
void combine_pool(const float* __restrict__ part, const float* __restrict__ bias,
                  unsigned short* __restrict__ out)
{
    constexpr int HO = HI/2, C4 = CO/4;
    constexpr size_t NPIX = (size_t)BATCH*HI*HI;
    int t = blockIdx.x*256 + threadIdx.x;
    if (t >= BATCH*HO*HO*C4) return;
    int c4 = t % C4;
    int r  = t / C4;
    int xo = r % HO, yo = (r/HO) % HO, img = r/(HO*HO);
    fx4 m = {-1e30f, -1e30f, -1e30f, -1e30f};
    #pragma unroll
    for (int iy = 0; iy < 2; iy++)
        #pragma unroll
        for (int ix = 0; ix < 2; ix++) {
            size_t pix = (size_t)img*HI*HI + (2*yo+iy)*HI + (2*xo+ix);
            fx4 s = {0.f,0.f,0.f,0.f};
            #pragma unroll
            for (int k = 0; k < KS; k++)
                s += *(const fx4*)&part[((size_t)k*NPIX + pix)*CO + c4*4];
            #pragma unroll
            for (int e = 0; e < 4; e++) m[e] = fmaxf(m[e], s[e]);
        }
    fx4 b4 = *(const fx4*)&bias[c4*4];
    us4 o;
    #pragma unroll
    for (int e = 0; e < 4; e++) o[e] = f2bf(fmaxf(m[e] + b4[e], 0.f));
    *(us4*)&out[((size_t)(img*HO+yo)*HO + xo)*CO + c4*4] = o;
}

// conv4b finish: sum KS=16 partials + bias + relu + engram mask + pool2
// -> X0 bf16 row-major [64][2048]
__global__ __launch_bounds__(256)
void combine4b(const float* __restrict__ part, const float* __restrict__ bias,
               const float* __restrict__ mask, unsigned short* __restrict__ X0)
{
    int t = blockIdx.x*256 + threadIdx.x;
    if (t >= BATCH*512) return;
    int b = t / 512, c = t % 512;
    float s[16];
    #pragma unroll
    for (int p = 0; p < 16; p++) s[p] = 0.f;
    #pragma unroll
    for (int k = 0; k < 16; k++)
        #pragma unroll
        for (int p = 0; p < 16; p++)
            s[p] += part[((size_t)k*1024 + b*16 + p)*512 + c];
    float mk = mask[b*512 + c], bb = bias[c];
    us4 o;
    #pragma unroll
    for (int py = 0; py < 2; py++)
        #pragma unroll
        for (int px = 0; px < 2; px++) {
            float m = fmaxf(fmaxf(s[(2*py)*4 + 2*px],     s[(2*py)*4 + 2*px+1]),
                            fmaxf(s[(2*py+1)*4 + 2*px],   s[(2*py+1)*4 + 2*px+1]));
            o[py*2+px] = f2bf(mk * fmaxf(m + bb, 0.f));
        }
    *(us4*)&X0[(size_t)b*2048 + c*4] = o;
}

// ---------------------------------------------------------------------------
// engram mask
// ---------------------------------------------------------------------------
__global__ void build_mask(const int* __restrict__ y, const int* __restrict__ btab,
                           float* __restrict__ mask)
{
    __shared__ float m[512];
    int b = blockIdx.x;
    int t = threadIdx.x;               // 128 threads
    for (int i = t; i < 512; i += 128) m[i] = 0.f;
    __syncthreads();
    int cls = y[b];
    int idx = btab[cls*128 + t];
    m[idx] = 1.0f;
    __syncthreads();
    for (int i = t; i < 512; i += 128) mask[b*512 + i] = m[i];
}

// ---------------------------------------------------------------------------
// MFMA FC: C[64,N] = X[64,K](bf16) @ W[N,K]^T(fp32 -> bf16 in-register).
// ---------------------------------------------------------------------------
template<int K, int NP, int NREAL, int KSO>
__global__ __launch_bounds__(256)
void fc_mfma(const unsigned short* __restrict__ X, const float* __restrict__ W,
             float* __restrict__ P)
{
    constexpr int KW = K / (KSO*4);
    constexpr int NI = KW / 32;
    __shared__ alignas(16) unsigned short XL[4][64][40];
    __shared__ alignas(16) float R[64][68];

    const int tid  = threadIdx.x;
    const int lane = tid & 63;
    const int wv   = __builtin_amdgcn_readfirstlane(tid >> 6);
    const int quad = lane >> 4;
    const int nn   = lane & 15;
    const int c0   = blockIdx.x * 64;
    const int ksb  = blockIdx.y;
    const int k0   = (ksb*4 + wv) * KW;

    fx4 acc[4][4];
    #pragma unroll
    for (int mf = 0; mf < 4; mf++)
        #pragma unroll
        for (int nf = 0; nf < 4; nf++) {
            fx4 z = {0.f,0.f,0.f,0.f};
            acc[mf][nf] = z;
        }

    #pragma unroll
    for (int kc = 0; kc < NI; kc++) {
        const int kw = k0 + kc*32;
        const unsigned short* xp = X + (size_t)lane*K + kw;
        us8 x0 = *(const us8*)(xp);
        us8 x1 = *(const us8*)(xp + 8);
        us8 x2 = *(const us8*)(xp + 16);
        us8 x3 = *(const us8*)(xp + 24);
        *(us8*)&XL[wv][lane][0]  = x0;
        *(us8*)&XL[wv][lane][8]  = x1;
        *(us8*)&XL[wv][lane][16] = x2;
        *(us8*)&XL[wv][lane][24] = x3;
        short8 b[4];
        #pragma unroll
        for (int nf = 0; nf < 4; nf++) {
            int c = c0 + nf*16 + nn;
            if (c > NREAL-1) c = NREAL-1;
            const float* wp = W + (size_t)c*K + kw + quad*8;
            float4 f0 = *(const float4*)(wp);
            float4 f1 = *(const float4*)(wp + 4);
            short8 t;
            t[0] = (short)f2bf(f0.x); t[1] = (short)f2bf(f0.y);
            t[2] = (short)f2bf(f0.z); t[3] = (short)f2bf(f0.w);
            t[4] = (short)f2bf(f1.x); t[5] = (short)f2bf(f1.y);
            t[6] = (short)f2bf(f1.z); t[7] = (short)f2bf(f1.w);
            b[nf] = t;
        }
        short8 a[4];
        #pragma unroll
        for (int mf = 0; mf < 4; mf++)
            a[mf] = *(const short8*)&XL[wv][mf*16 + nn][quad*8];
        #pragma unroll
        for (int mf = 0; mf < 4; mf++)
            #pragma unroll
            for (int nf = 0; nf < 4; nf++)
                acc[mf][nf] = __builtin_amdgcn_mfma_f32_16x16x32_bf16(
                    a[mf], b[nf], acc[mf][nf], 0, 0, 0);
    }

    for (int ww = 0; ww < 4; ww++) {
        __syncthreads();
        if (wv == ww) {
            #pragma unroll
            for (int mf = 0; mf < 4; mf++)
                #pragma unroll
                for (int nf = 0; nf < 4; nf++) {
                    int n = nf*16 + nn;
                    #pragma unroll
                    for (int r = 0; r < 4; r++) {
                        int m = mf*16 + quad*4 + r;
                        float v = acc[mf][nf][r];
                        if (ww) v += R[m][n];
                        R[m][n] = v;
                    }
                }
        }
    }
    __syncthreads();
    {
        int m  = tid >> 2;
        int n0 = (tid & 3) * 16;
        float* dst = P + ((size_t)ksb*64 + m)*NP + c0 + n0;
        #pragma unroll
        for (int j = 0; j < 4; j++) {
            fx4 v = *(const fx4*)&R[m][n0 + j*4];
            *(fx4*)(dst + j*4) = v;
        }
    }
}

template<int N, int KS>
__global__ __launch_bounds__(256)
void fc_combine_bf16(const float* __restrict__ P, const float* __restrict__ bias,
                     unsigned short* __restrict__ Xo)
{
    int t = blockIdx.x*256 + threadIdx.x;
    if (t >= 64*(N/4)) return;
    int c4 = t % (N/4);
    int b  = t / (N/4);
    fx4 s = *(const fx4*)&bias[c4*4];
    #pragma unroll
    for (int ks = 0; ks < KS; ks++)
        s += *(const fx4*)&P[((size_t)ks*64 + b)*N + c4*4];
    us4 o;
    #pragma unroll
    for (int r = 0; r < 4; r++) o[r] = f2bf(fmaxf(s[r], 0.f));
    *(us4*)&Xo[(size_t)b*N + c4*4] = o;
}

__global__ __launch_bounds__(256)
void fc3_combine(const float* __restrict__ P, const float* __restrict__ bias,
                 float* __restrict__ out)
{
    int t = blockIdx.x*256 + threadIdx.x;
    if (t >= 64*1000) return;
    int b = t / 1000, c = t % 1000;
    float s = bias[c];
    #pragma unroll
    for (int ks = 0; ks < 32; ks++)
        s += P[((size_t)ks*64 + b)*1024 + c];
    out[t] = s;
}

// ---------------------------------------------------------------------------
extern "C" void kernel_launch(void* const* d_in, const int* in_sizes, int n_in,
                              void* d_out, int out_size, void* d_ws, size_t ws_size,
                              hipStream_t stream)
{
    const float* x    = (const float*)d_in[0];
    const int*   y    = (const int*)  d_in[1];
    const int*   btab = (const int*)  d_in[2];
    const float* cw0  = (const float*)d_in[3];  const float* cb0  = (const float*)d_in[4];
    const float* cw1  = (const float*)d_in[5];  const float* cb1  = (const float*)d_in[6];
    const float* cw2a = (const float*)d_in[7];  const float* cb2a = (const float*)d_in[8];
    const float* cw2b = (const float*)d_in[9];  const float* cb2b = (const float*)d_in[10];
    const float* cw3a = (const float*)d_in[11]; const float* cb3a = (const float*)d_in[12];
    const float* cw3b = (const float*)d_in[13]; const float* cb3b = (const float*)d_in[14];
    const float* cw4a = (const float*)d_in[15]; const float* cb4a = (const float*)d_in[16];
    const float* cw4b = (const float*)d_in[17]; const float* cb4b = (const float*)d_in[18];
    const float* fw1  = (const float*)d_in[19]; const float* fb1  = (const float*)d_in[20];
    const float* fw2  = (const float*)d_in[21]; const float* fb2  = (const float*)d_in[22];
    const float* fw3  = (const float*)d_in[23]; const float* fb3  = (const float*)d_in[24];
    (void)in_sizes; (void)n_in; (void)out_size; (void)ws_size;

    float* ws = (float*)d_ws;
    unsigned short* ActA = (unsigned short*)(ws);             // 2,097,152 f region
    unsigned short* ActB = (unsigned short*)(ws + 2097152);   // 1,048,576 f
    float*          Pp   = ws + 3145728;                      // 8,388,608 f partials
    unsigned short* Wp   = (unsigned short*)(ws + 11534336);  // 9,216,000 bf16
    float*          M    = ws + 16142336;                     // 32,768 f
    unsigned short* X0   = (unsigned short*)(ws + 16175104);  // [64][2048] bf16
    unsigned short* X1   = (unsigned short*)(ws + 16240640);  // [64][4096] bf16
    unsigned short* X2   = (unsigned short*)(ws + 16371712);  // [64][4096] bf16

    // weight prepack (conv1..conv4b)
    PPAll pa;
    const float* srcs[7] = {cw1, cw2a, cw2b, cw3a, cw3b, cw4a, cw4b};
    const unsigned long long doffs[7] = {0, 73728, 368640, 958464, 2138112, 4497408, 6856704};
    const int cins[7]  = {64, 128, 256, 256, 512, 512, 512};
    const int couts[7] = {128, 256, 256, 512, 512, 512, 512};
    const int ends[7]  = {8192, 40960, 106496, 237568, 499712, 761856, 1024000};
    for (int i = 0; i < 7; i++) {
        pa.src[i] = srcs[i]; pa.dstoff[i] = doffs[i];
        pa.cin[i] = cins[i]; pa.cout[i] = couts[i]; pa.end[i] = ends[i];
    }
    prepack<<<4000, 256, 0, stream>>>(pa, Wp);

    // conv0: x -> ActA [64][32][32][64] bf16 NHWC
    conv0_kernel<<<1024, 256, 0, stream>>>(x, cw0, cb0, ActA);
    // conv1 + relu + pool (KS=1, direct): -> ActB [64][16][16][128]
    conv_mfma<64,128,32,2,2,1,1,true><<<dim3(512,1,1),256,0,stream>>>(ActA, Wp+0, cb1, ActB);
    // conv2a (KS=2): partials -> ActA [64][16][16][256]
    conv_mfma<128,256,16,2,2,1,2,false><<<dim3(128,2,2),256,0,stream>>>(ActB, Wp+73728, cb2a, Pp);
    combine_nhwc<2, 16384, 256><<<4096,256,0,stream>>>(Pp, cb2a, ActA);
    // conv2b (KS=2) + pool in combine: -> ActB [64][8][8][256]
    conv_mfma<256,256,16,2,2,1,2,false><<<dim3(128,2,2),256,0,stream>>>(ActA, Wp+368640, cb2b, Pp);
    combine_pool<2, 16, 256><<<1024,256,0,stream>>>(Pp, cb2b, ActB);
    // conv3a (KS=4): -> ActA [64][8][8][512]
    conv_mfma<256,512,8,4,1,1,4,false><<<dim3(64,2,4),256,0,stream>>>(ActB, Wp+958464, cb3a, Pp);
    combine_nhwc<4, 4096, 512><<<2048,256,0,stream>>>(Pp, cb3a, ActA);
    // conv3b (KS=4) + pool in combine: -> ActB [64][4][4][512]
    conv_mfma<512,512,8,4,1,1,4,false><<<dim3(64,2,4),256,0,stream>>>(ActA, Wp+2138112, cb3b, Pp);
    combine_pool<4, 8, 512><<<512,256,0,stream>>>(Pp, cb3b, ActB);
    // conv4a (KS=16): -> ActA [64][4][4][512]
    conv_mfma<512,512,4,4,1,4,16,false><<<dim3(16,2,16),256,0,stream>>>(ActB, Wp+4497408, cb4a, Pp);
    combine_nhwc<16, 1024, 512><<<512,256,0,stream>>>(Pp, cb4a, ActA);
    // engram mask
    build_mask<<<64,128,0,stream>>>(y, btab, M);
    // conv4b (KS=16): combine fuses mask + pool -> X0 [64][2048] bf16
    conv_mfma<512,512,4,4,1,4,16,false><<<dim3(16,2,16),256,0,stream>>>(ActA, Wp+6856704, cb4b, Pp);
    combine4b<<<128,256,0,stream>>>(Pp, cb4b, M, X0);
    // classifier
    fc_mfma<2048,4096,4096,8><<<dim3(64,8),256,0,stream>>>(X0, fw1, Pp);
    fc_combine_bf16<4096,8><<<256,256,0,stream>>>(Pp, fb1, X1);
    fc_mfma<4096,4096,4096,8><<<dim3(64,8),256,0,stream>>>(X1, fw2, Pp);
    fc_combine_bf16<4096,8><<<256,256,0,stream>>>(Pp, fb2, X2);
    fc_mfma<4096,1024,1000,32><<<dim3(16,32),256,0,stream>>>(X2, fw3, Pp);
    fc3_combine<<<250,256,0,stream>>>(Pp, fb3, (float*)d_out);
}